// Round 9
// baseline (100.419 us; speedup 1.0000x reference)
//
#include <hip/hip_runtime.h>
#include <math.h>

#define NN 8192
#define DD 256
#define MARGIN 0.2f
#define SL 16                // candidate slices (grid.x)
#define CPS (NN / SL)        // 512 candidates per slice
#define TILES (CPS / 128)    // 4 tiles per block
#define IMAX 0x7fffffff

typedef __attribute__((ext_vector_type(8))) short bf16x8;  // 8 bf16 (4 VGPRs)
typedef __attribute__((ext_vector_type(4))) float f32x4;
typedef unsigned int u32;
typedef unsigned short u16;

static __device__ __forceinline__ u16 f2bf(float f) {   // RNE fp32 -> bf16
    u32 u = __float_as_uint(f);
    return (u16)((u + 0x7fffu + ((u >> 16) & 1u)) >> 16);
}

// builtin's size/offset must be LITERAL constants -> offset always 0,
// k-dependent offsets folded into the pointer operand instead.
#define GLOAD16(g, l)                                                             \
    __builtin_amdgcn_global_load_lds(                                             \
        (const __attribute__((address_space(1))) void*)(g),                       \
        (__attribute__((address_space(3))) void*)(l), 16, 0, 0)

// ---------- kernel 1: fused kprep (blocks 0..2047) + kclass (2048..2175) ----------
static __device__ __forceinline__ void comb2(int& a1, int& a2, int b1, int b2) {
    const int lo = min(a1, b1);
    const int hi = max(a1, b1);
    a2 = min(hi, min(a2, b2));
    a1 = lo;
}

__global__ void kprepclass(const float* __restrict__ emb, const int* __restrict__ labels,
                           u16* __restrict__ ENb, float* __restrict__ invn,
                           int* __restrict__ posidx) {
    const int tid = threadIdx.x;
    if (blockIdx.x < 2048) {   // ---- kprep: norms + normalized bf16 matrix ----
        const int wid = tid >> 6, l = tid & 63;
        const int row = blockIdx.x * 4 + wid;
        const float4 v = *(const float4*)&emb[(size_t)row * DD + l * 4];
        float ss = v.x * v.x + v.y * v.y + v.z * v.z + v.w * v.w;
#pragma unroll
        for (int o = 1; o < 64; o <<= 1) ss += __shfl_xor(ss, o);
        const float inv = 1.0f / fmaxf(sqrtf(ss), 1e-12f);
        if (l == 0) invn[row] = inv;
        ushort4 o4;
        o4.x = f2bf(v.x * inv); o4.y = f2bf(v.y * inv);
        o4.z = f2bf(v.z * inv); o4.w = f2bf(v.w * inv);
        *(ushort4*)&ENb[(size_t)row * DD + l * 4] = o4;
    } else {                   // ---- kclass: first two indices of class -> posidx ----
        const int c = blockIdx.x - 2048;
        int m1 = IMAX, m2 = IMAX;
        for (int j = tid; j < NN; j += 256) {   // ascending -> m1 < m2 per thread
            if (labels[j] == c) {
                if (m1 == IMAX) m1 = j;
                else if (m2 == IMAX) m2 = j;
            }
        }
#pragma unroll
        for (int o = 1; o < 64; o <<= 1)
            comb2(m1, m2, __shfl_xor(m1, o), __shfl_xor(m2, o));
        __shared__ int s1[4], s2[4];
        __shared__ int bj1, bj2;
        const int wave = tid >> 6, lane = tid & 63;
        if (lane == 0) { s1[wave] = m1; s2[wave] = m2; }
        __syncthreads();
        if (tid == 0) {
            comb2(m1, m2, s1[1], s2[1]);
            comb2(m1, m2, s1[2], s2[2]);
            comb2(m1, m2, s1[3], s2[3]);
            bj1 = m1; bj2 = m2;
        }
        __syncthreads();
        const int j1 = bj1, j2 = bj2;
        for (int j = tid; j < NN; j += 256)     // every j has exactly one class
            if (labels[j] == c) posidx[j] = (j2 == IMAX) ? -1 : ((j == j1) ? j2 : j1);
    }
}

// ---------- kernel 3: exact fp32 d_ap ----------
__global__ void kdap(const float* __restrict__ emb, const float* __restrict__ invn,
                     const int* __restrict__ posidx, float* __restrict__ dap) {
    const int wid = threadIdx.x >> 6, l = threadIdx.x & 63;
    const int i = blockIdx.x * 4 + wid;
    const int p = posidx[i];
    float dv = 0.0f;
    if (p >= 0) {   // uniform per wave
        const float4 a = *(const float4*)&emb[(size_t)i * DD + l * 4];
        const float4 b = *(const float4*)&emb[(size_t)p * DD + l * 4];
        float s = a.x * b.x + a.y * b.y + a.z * b.z + a.w * b.w;
#pragma unroll
        for (int o = 1; o < 64; o <<= 1) s += __shfl_xor(s, o);
        const float sim = s * invn[i] * invn[p];
        dv = fminf(fmaxf(1.0f - sim, 0.0f), 2.0f);
    }
    if (l == 0) dap[i] = dv;
}

// ---------- kernel 4: MFMA mining ----------
// Counted-vmcnt pipeline at BK=32: 36.8 KB LDS -> 4 blocks/CU (16 waves),
// STAGE = 4 DMAs -> s_waitcnt vmcnt(4) steady state, vmcnt(0) only at tail.
// Swizzle: phys chunk = logical ^ (row&3); stage source chunk (t&3)^((t>>2)&3).
__global__ __launch_bounds__(256, 4) void kmine(
    const u16* __restrict__ ENb, const int* __restrict__ labels,
    const float* __restrict__ dap, float* __restrict__ pM1, float* __restrict__ pMN)
{
    __shared__ __align__(16) u16 As0[128 * 32], As1[128 * 32];   // 8 KB each
    __shared__ __align__(16) u16 Bs0[128 * 32], Bs1[128 * 32];
    __shared__ __align__(16) int Ls[CPS];                        // 2 KB labels
    __shared__ float RedN[2][128], RedS[2][128];

    const int tid = threadIdx.x;
    const int l = tid & 63;
    const int wid = tid >> 6;
    const int wr = wid >> 1;      // candidate half (M)
    const int wc = wid & 1;       // anchor half (N)
    const int slice = blockIdx.x;
    const int a0 = blockIdx.y * 128;

    const int frow = l & 15;      // row within 16x16 subtile
    const int fq = l >> 4;        // k-chunk 0..3 within BK=32
    const int fswz = (fq ^ (frow & 3)) * 8;          // swizzled read chunk (u16 idx)
    const int lch = (tid & 3) ^ ((tid >> 2) & 3);    // swizzled source chunk (stage)

    // --- prologue register loads (settle before first use; outside step ledger) ---
    if (tid < 128) {
        const int4 lv = *(const int4*)&labels[slice * CPS + tid * 4];
        *(int4*)&Ls[tid * 4] = lv;
    }
    int la[4]; float hiv[4];
#pragma unroll
    for (int n = 0; n < 4; ++n) {
        const int ai = a0 + wc * 64 + n * 16 + frow;
        la[n] = labels[ai];
        hiv[n] = 1.0f - dap[ai];
    }

    // staged-source pointers: 4 threads x 16B (permuted) = 64B per row
    const char* ENc = (const char*)ENb;
    const char* ag = ENc + (size_t)(slice * CPS + (tid >> 2)) * 512 + lch * 16;
    const char* bg = ENc + (size_t)(a0        + (tid >> 2)) * 512 + lch * 16;

    // one step = 4 DMAs: A rows 0-63 / 64-127, B rows 0-63 / 64-127 (8 KB each mat)
#define STAGE(ABUF, BBUF, AP, BP) do {                        \
        GLOAD16((AP),         &ABUF[tid * 8]);                \
        GLOAD16((AP) + 32768, &ABUF[tid * 8 + 2048]);         \
        GLOAD16((BP),         &BBUF[tid * 8]);                \
        GLOAD16((BP) + 32768, &BBUF[tid * 8 + 2048]);         \
    } while (0)

#define COMPUTE(RA, RB, FIRST) do {                                               \
        bf16x8 af[4], bf[4];                                                      \
        _Pragma("unroll")                                                         \
        for (int m = 0; m < 4; ++m)                                               \
            af[m] = *(const bf16x8*)&RA[(wr * 64 + m * 16 + frow) * 32 + fswz];   \
        _Pragma("unroll")                                                         \
        for (int n = 0; n < 4; ++n)                                               \
            bf[n] = *(const bf16x8*)&RB[(wc * 64 + n * 16 + frow) * 32 + fswz];   \
        __builtin_amdgcn_s_setprio(1);                                            \
        _Pragma("unroll")                                                         \
        for (int m = 0; m < 4; ++m)                                               \
            _Pragma("unroll")                                                     \
            for (int n = 0; n < 4; ++n)                                           \
                acc[m][n] = __builtin_amdgcn_mfma_f32_16x16x32_bf16(              \
                    af[m], bf[n], (FIRST) ? Zv : acc[m][n], 0, 0, 0);             \
        __builtin_amdgcn_s_setprio(0);                                            \
    } while (0)

    float mN[4], m1[4];
#pragma unroll
    for (int n = 0; n < 4; ++n) { mN[n] = -INFINITY; m1[n] = -INFINITY; }
    const f32x4 Zv = {0.f, 0.f, 0.f, 0.f};
    f32x4 acc[4][4];

    // prologue: stage tile0/kc0, make labels visible
    STAGE(As0, Bs0, ag, bg);
    asm volatile("s_waitcnt lgkmcnt(0)" ::: "memory");
    __builtin_amdgcn_s_barrier();

#pragma unroll
    for (int t = 0; t < TILES; ++t) {
        const char* at = ag + t * 65536;
#pragma unroll
        for (int k = 0; k < 8; ++k) {
            // issue stage(s+1) into the other buffer (freed by prev end barrier)
            if (k < 7) {
                if (k & 1) STAGE(As0, Bs0, at + (k + 1) * 64, bg + (k + 1) * 64);
                else       STAGE(As1, Bs1, at + (k + 1) * 64, bg + (k + 1) * 64);
            } else if (t < TILES - 1) {
                STAGE(As0, Bs0, at + 65536, bg);   // k=7 (odd) -> next is buf0
            }
            // counted wait: stage(s) landed, stage(s+1)'s 4 loads stay in flight
            if (t == TILES - 1 && k == 7)
                asm volatile("s_waitcnt vmcnt(0)" ::: "memory");
            else
                asm volatile("s_waitcnt vmcnt(4)" ::: "memory");
            __builtin_amdgcn_s_barrier();

            if (k & 1) COMPUTE(As1, Bs1, false);
            else if (k == 0) COMPUTE(As0, Bs0, true);
            else COMPUTE(As0, Bs0, false);

            if (k == 7) {   // tile epilogue: mask + running maxes
                int lcv[16];
#pragma unroll
                for (int m = 0; m < 4; ++m) {
                    const int4 v = *(const int4*)&Ls[t * 128 + wr * 64 + m * 16 + fq * 4];
                    lcv[m * 4 + 0] = v.x; lcv[m * 4 + 1] = v.y;
                    lcv[m * 4 + 2] = v.z; lcv[m * 4 + 3] = v.w;
                }
#pragma unroll
                for (int n = 0; n < 4; ++n) {
#pragma unroll
                    for (int m = 0; m < 4; ++m)
#pragma unroll
                        for (int r = 0; r < 4; ++r) {
                            const float sv = acc[m][n][r];
                            const float sel = (lcv[m * 4 + r] != la[n]) ? sv : -INFINITY;
                            mN[n] = fmaxf(mN[n], sel);
                            m1[n] = fmaxf(m1[n], (sel < hiv[n]) ? sel : -INFINITY);
                        }
                }
            }
            __builtin_amdgcn_s_barrier();   // frees the just-computed buffer
        }
    }
#undef STAGE
#undef COMPUTE

    // reduce the 4 candidate row-groups (lanes l, l^16, l^32, l^48 share anchor)
#pragma unroll
    for (int n = 0; n < 4; ++n) {
        mN[n] = fmaxf(mN[n], __shfl_xor(mN[n], 16));
        mN[n] = fmaxf(mN[n], __shfl_xor(mN[n], 32));
        m1[n] = fmaxf(m1[n], __shfl_xor(m1[n], 16));
        m1[n] = fmaxf(m1[n], __shfl_xor(m1[n], 32));
    }
    if (fq == 0) {
#pragma unroll
        for (int n = 0; n < 4; ++n) {
            RedN[wr][wc * 64 + n * 16 + frow] = mN[n];
            RedS[wr][wc * 64 + n * 16 + frow] = m1[n];
        }
    }
    __syncthreads();
    if (tid < 128) {   // combine the two candidate halves, write partials
        pMN[slice * NN + a0 + tid] = fmaxf(RedN[0][tid], RedN[1][tid]);
        pM1[slice * NN + a0 + tid] = fmaxf(RedS[0][tid], RedS[1][tid]);
    }
}

// ---------- kernel 5: combine slices -> per-block partial sums ----------
__global__ void kcombine(const int* __restrict__ posidx, const float* __restrict__ dap,
                         const float* __restrict__ pM1, const float* __restrict__ pMN,
                         float* __restrict__ partials)
{
    const int i = blockIdx.x * 256 + threadIdx.x;
    float loss = 0.0f, cnt = 0.0f;
    if (posidx[i] >= 0) {
        float s1 = -INFINITY, sN = -INFINITY;
#pragma unroll
        for (int s = 0; s < SL; ++s) {
            s1 = fmaxf(s1, pM1[s * NN + i]);
            sN = fmaxf(sN, pMN[s * NN + i]);
        }
        const float da = dap[i];
        const float lo = 1.0f - da - MARGIN;
        const float M = (s1 > lo) ? s1 : sN;   // has_semi ? best semi : hardest
        const float dan = fminf(fmaxf(1.0f - M, 0.0f), 2.0f);
        loss = fmaxf(da - dan + MARGIN, 0.0f);
        cnt = 1.0f;
    }
#pragma unroll
    for (int off = 1; off < 64; off <<= 1) {
        loss += __shfl_xor(loss, off);
        cnt  += __shfl_xor(cnt, off);
    }
    __shared__ float sl[4], sc[4];
    const int wave = threadIdx.x >> 6, lane = threadIdx.x & 63;
    if (lane == 0) { sl[wave] = loss; sc[wave] = cnt; }
    __syncthreads();
    if (threadIdx.x == 0) {
        partials[blockIdx.x]      = sl[0] + sl[1] + sl[2] + sl[3];
        partials[32 + blockIdx.x] = sc[0] + sc[1] + sc[2] + sc[3];
    }
}

// ---------- kernel 6: final scalar ----------
__global__ void kfinal(const float* __restrict__ partials, float* __restrict__ out) {
    const int t = threadIdx.x;  // 64
    float L = (t < 32) ? partials[t] : 0.0f;
    float C = (t < 32) ? partials[32 + t] : 0.0f;
#pragma unroll
    for (int off = 1; off < 64; off <<= 1) {
        L += __shfl_xor(L, off);
        C += __shfl_xor(C, off);
    }
    if (t == 0) out[0] = (C > 0.0f) ? (L / C) : 0.0f;
}

extern "C" void kernel_launch(void* const* d_in, const int* in_sizes, int n_in,
                              void* d_out, int out_size, void* d_ws, size_t ws_size,
                              hipStream_t stream) {
    const float* emb  = (const float*)d_in[0];
    const int* labels = (const int*)d_in[1];
    float* out = (float*)d_out;

    char* w = (char*)d_ws;
    u16*   ENb  = (u16*)w;                       w += (size_t)NN * DD * 2;   // 4 MB
    float* invn = (float*)w;                     w += NN * 4;
    float* dapv = (float*)w;                     w += NN * 4;
    int*   posi = (int*)w;                       w += NN * 4;
    float* pM1  = (float*)w;                     w += (size_t)SL * NN * 4;   // 512 KB
    float* pMN  = (float*)w;                     w += (size_t)SL * NN * 4;   // 512 KB
    float* parts = (float*)w;

    kprepclass<<<2048 + 128, 256, 0, stream>>>(emb, labels, ENb, invn, posi);
    kdap<<<NN / 4, 256, 0, stream>>>(emb, invn, posi, dapv);
    kmine<<<dim3(SL, NN / 128), 256, 0, stream>>>(ENb, labels, dapv, pM1, pMN);
    kcombine<<<NN / 256, 256, 0, stream>>>(posi, dapv, pM1, pMN, parts);
    kfinal<<<1, 64, 0, stream>>>(parts, out);
}

// Round 10
// 58.860 us; speedup vs baseline: 1.7061x; 1.7061x over previous
//
#include <hip/hip_runtime.h>
#include <math.h>

#define NN 8192
#define DD 256
#define MARGIN 0.2f
#define SL 16                // candidate slices (grid.x)
#define CPS (NN / SL)        // 512 candidates per slice
#define TILES (CPS / 128)    // 4 tiles per block
#define IMAX 0x7fffffff

typedef __attribute__((ext_vector_type(4))) float f32x4;
typedef __attribute__((ext_vector_type(2))) long long2_t;
typedef unsigned int u32;
typedef unsigned short u16;
typedef unsigned char u8;

// ---- software RNE fp32 -> OCP e4m3fn (no inf; max 448; bias 7) ----
static __device__ __forceinline__ u8 f2e4m3(float x) {
    float a = fabsf(x);
    a = fminf(a, 448.0f);
    const u32 s = (__float_as_uint(x) >> 31) << 7;
    if (a < 0.015625f) {                      // subnormal range: step 2^-9
        const int m = (int)rintf(a * 512.0f); // 0..8 (8 carries into exp=1 naturally)
        return (u8)(s | m);
    }
    u32 u = __float_as_uint(a);
    u += 0x7FFFF + ((u >> 20) & 1);           // RNE into 3-bit mantissa
    const u32 e = (u >> 23) - 120;            // -127 + 7
    return (u8)(s | (e << 3) | ((u >> 20) & 7));
}

// builtin's size/offset must be LITERAL constants
#define GLOAD16(g, l)                                                             \
    __builtin_amdgcn_global_load_lds(                                             \
        (const __attribute__((address_space(1))) void*)(g),                       \
        (__attribute__((address_space(3))) void*)(l), 16, 0, 0)

// ---------- kernel 1: fused kprep (blocks 0..2047) + kclass (2048..2175) ----------
// kprep writes E8 in an h-interleaved permuted layout: within each row's 64-elem
// kc-block, global byte g = kc*64 + c*16 + h*8 + o  holds logical k = kc*64 + h*32 + c*8 + o.
// So each 16-B chunk c = [8B of k-half0][8B of k-half1] = one MFMA fragment pair.
static __device__ __forceinline__ void comb2(int& a1, int& a2, int b1, int b2) {
    const int lo = min(a1, b1);
    const int hi = max(a1, b1);
    a2 = min(hi, min(a2, b2));
    a1 = lo;
}

__global__ void kprepclass(const float* __restrict__ emb, const int* __restrict__ labels,
                           u8* __restrict__ E8, float* __restrict__ invn,
                           int* __restrict__ posidx) {
    const int tid = threadIdx.x;
    if (blockIdx.x < 2048) {   // ---- kprep ----
        const int wid = tid >> 6, l = tid & 63;
        const int row = blockIdx.x * 4 + wid;
        const float4 v = *(const float4*)&emb[(size_t)row * DD + l * 4];
        float ss = v.x * v.x + v.y * v.y + v.z * v.z + v.w * v.w;
#pragma unroll
        for (int o = 1; o < 64; o <<= 1) ss += __shfl_xor(ss, o);
        const float inv = 1.0f / fmaxf(sqrtf(ss), 1e-12f);
        if (l == 0) invn[row] = inv;
        const u32 b0 = f2e4m3(v.x * inv), b1 = f2e4m3(v.y * inv);
        const u32 b2 = f2e4m3(v.z * inv), b3 = f2e4m3(v.w * inv);
        const u32 packed = b0 | (b1 << 8) | (b2 << 16) | (b3 << 24);
        // lane l covers k = 4l..4l+3 -> dest byte g in permuted layout
        const int kc = l >> 4, h = (l >> 3) & 1, c = (l >> 1) & 3, o = (l & 1) * 4;
        const int g = kc * 64 + c * 16 + h * 8 + o;
        *(u32*)&E8[(size_t)row * DD + g] = packed;
    } else {                   // ---- kclass ----
        const int c = blockIdx.x - 2048;
        int m1 = IMAX, m2 = IMAX;
        for (int j = tid; j < NN; j += 256) {
            if (labels[j] == c) {
                if (m1 == IMAX) m1 = j;
                else if (m2 == IMAX) m2 = j;
            }
        }
#pragma unroll
        for (int o = 1; o < 64; o <<= 1)
            comb2(m1, m2, __shfl_xor(m1, o), __shfl_xor(m2, o));
        __shared__ int s1[4], s2[4];
        __shared__ int bj1, bj2;
        const int wave = tid >> 6, lane = tid & 63;
        if (lane == 0) { s1[wave] = m1; s2[wave] = m2; }
        __syncthreads();
        if (tid == 0) {
            comb2(m1, m2, s1[1], s2[1]);
            comb2(m1, m2, s1[2], s2[2]);
            comb2(m1, m2, s1[3], s2[3]);
            bj1 = m1; bj2 = m2;
        }
        __syncthreads();
        const int j1 = bj1, j2 = bj2;
        for (int j = tid; j < NN; j += 256)
            if (labels[j] == c) posidx[j] = (j2 == IMAX) ? -1 : ((j == j1) ? j2 : j1);
    }
}

// ---------- kernel 3: exact fp32 d_ap ----------
__global__ void kdap(const float* __restrict__ emb, const float* __restrict__ invn,
                     const int* __restrict__ posidx, float* __restrict__ dap) {
    const int wid = threadIdx.x >> 6, l = threadIdx.x & 63;
    const int i = blockIdx.x * 4 + wid;
    const int p = posidx[i];
    float dv = 0.0f;
    if (p >= 0) {   // uniform per wave
        const float4 a = *(const float4*)&emb[(size_t)i * DD + l * 4];
        const float4 b = *(const float4*)&emb[(size_t)p * DD + l * 4];
        float s = a.x * b.x + a.y * b.y + a.z * b.z + a.w * b.w;
#pragma unroll
        for (int o = 1; o < 64; o <<= 1) s += __shfl_xor(s, o);
        const float sim = s * invn[i] * invn[p];
        dv = fminf(fmaxf(1.0f - sim, 0.0f), 2.0f);
    }
    if (l == 0) dap[i] = dv;
}

// ---------- kernel 4: fp8 MFMA mining, R7's counted-vmcnt schedule ----------
// LDS row = 64 B (BK=64 fp8), 4 pair-slots of 16 B; phys slot p holds logical
// chunk c = p ^ ((row>>1)&3) -> ds_read_b128 is 2-way (free) across 16 rows.
// One b128 = both K-halves (long2). STAGE = 4 DMAs -> vmcnt(4) steady, 0 at tail.
__global__ __launch_bounds__(256) void kmine(
    const u8* __restrict__ E8, const int* __restrict__ labels,
    const float* __restrict__ dap, float* __restrict__ pM1, float* __restrict__ pMN)
{
    __shared__ __align__(16) u8 As0[128 * 64], As1[128 * 64];   // 8 KB each
    __shared__ __align__(16) u8 Bs0[128 * 64], Bs1[128 * 64];
    __shared__ __align__(16) int Ls[CPS];                       // 2 KB labels
    __shared__ float RedN[2][128], RedS[2][128];

    const int tid = threadIdx.x;
    const int l = tid & 63;
    const int wid = tid >> 6;
    const int wr = wid >> 1;      // candidate half (M)
    const int wc = wid & 1;       // anchor half (N)
    const int slice = blockIdx.x;
    const int a0 = blockIdx.y * 128;

    const int frow = l & 15;      // row within 16x16 subtile
    const int fq = l >> 4;        // k-chunk 0..3 (8 fp8 each, per half)
    const int prd = (fq ^ ((frow >> 1) & 3)) * 16;   // swizzled read slot (bytes)
    const int csrc = (tid & 3) ^ ((tid >> 3) & 3);   // swizzled source chunk (stage)

    // --- prologue loads (outside the step ledger) ---
    if (tid < 128) {
        const int4 lv = *(const int4*)&labels[slice * CPS + tid * 4];
        *(int4*)&Ls[tid * 4] = lv;
    }
    int la[4]; float hiv[4];
#pragma unroll
    for (int n = 0; n < 4; ++n) {
        const int ai = a0 + wc * 64 + n * 16 + frow;
        la[n] = labels[ai];
        hiv[n] = 1.0f - dap[ai];
    }

    // staged-source pointers: 4 threads x 16B (slot-permuted) = one 64-B kc-block/row
    const char* Ec = (const char*)E8;
    const char* agp = Ec + (size_t)(slice * CPS + (tid >> 2)) * 256 + csrc * 16;
    const char* bgp = Ec + (size_t)(a0        + (tid >> 2)) * 256 + csrc * 16;

    // one step = 4 DMAs: A rows 0-63 / 64-127, B rows 0-63 / 64-127
#define STAGE(AB, BB, AP, BP) do {                      \
        GLOAD16((AP),         &AB[tid * 16]);           \
        GLOAD16((AP) + 16384, &AB[tid * 16 + 4096]);    \
        GLOAD16((BP),         &BB[tid * 16]);           \
        GLOAD16((BP) + 16384, &BB[tid * 16 + 4096]);    \
    } while (0)

#define COMPUTE(RA, RB, FIRST) do {                                               \
        long2_t a2[4], b2[4];                                                     \
        _Pragma("unroll")                                                         \
        for (int m = 0; m < 4; ++m)                                               \
            a2[m] = *(const long2_t*)&RA[(wr * 64 + m * 16 + frow) * 64 + prd];   \
        _Pragma("unroll")                                                         \
        for (int n = 0; n < 4; ++n)                                               \
            b2[n] = *(const long2_t*)&RB[(wc * 64 + n * 16 + frow) * 64 + prd];   \
        __builtin_amdgcn_s_setprio(1);                                            \
        _Pragma("unroll")                                                         \
        for (int m = 0; m < 4; ++m)                                               \
            _Pragma("unroll")                                                     \
            for (int n = 0; n < 4; ++n)                                           \
                acc[m][n] = __builtin_amdgcn_mfma_f32_16x16x32_fp8_fp8(           \
                    a2[m].x, b2[n].x, (FIRST) ? Zv : acc[m][n], 0, 0, 0);         \
        _Pragma("unroll")                                                         \
        for (int m = 0; m < 4; ++m)                                               \
            _Pragma("unroll")                                                     \
            for (int n = 0; n < 4; ++n)                                           \
                acc[m][n] = __builtin_amdgcn_mfma_f32_16x16x32_fp8_fp8(           \
                    a2[m].y, b2[n].y, acc[m][n], 0, 0, 0);                        \
        __builtin_amdgcn_s_setprio(0);                                            \
    } while (0)

    float mN[4], m1[4];
#pragma unroll
    for (int n = 0; n < 4; ++n) { mN[n] = -INFINITY; m1[n] = -INFINITY; }
    const f32x4 Zv = {0.f, 0.f, 0.f, 0.f};
    f32x4 acc[4][4];

    // prologue: stage tile0/kc0, make labels visible
    STAGE(As0, Bs0, agp, bgp);
    asm volatile("s_waitcnt lgkmcnt(0)" ::: "memory");
    __builtin_amdgcn_s_barrier();

#pragma unroll
    for (int t = 0; t < TILES; ++t) {
        const char* at = agp + t * 32768;
        // sk=0: stage kc1 -> buf1; compute buf0 (kc0, fresh acc)
        STAGE(As1, Bs1, at + 64, bgp + 64);
        asm volatile("s_waitcnt vmcnt(4)" ::: "memory");
        __builtin_amdgcn_s_barrier();
        COMPUTE(As0, Bs0, true);
        __builtin_amdgcn_s_barrier();
        // sk=1: stage kc2 -> buf0; compute buf1 (kc1)
        STAGE(As0, Bs0, at + 128, bgp + 128);
        asm volatile("s_waitcnt vmcnt(4)" ::: "memory");
        __builtin_amdgcn_s_barrier();
        COMPUTE(As1, Bs1, false);
        __builtin_amdgcn_s_barrier();
        // sk=2: stage kc3 -> buf1; compute buf0 (kc2)
        STAGE(As1, Bs1, at + 192, bgp + 192);
        asm volatile("s_waitcnt vmcnt(4)" ::: "memory");
        __builtin_amdgcn_s_barrier();
        COMPUTE(As0, Bs0, false);
        __builtin_amdgcn_s_barrier();
        // sk=3: stage next tile kc0 -> buf0; compute buf1 (kc3); epilogue
        if (t < TILES - 1) {
            STAGE(As0, Bs0, at + 32768, bgp);
            asm volatile("s_waitcnt vmcnt(4)" ::: "memory");
        } else {
            asm volatile("s_waitcnt vmcnt(0)" ::: "memory");
        }
        __builtin_amdgcn_s_barrier();
        COMPUTE(As1, Bs1, false);
        {   // tile epilogue: mask + running maxes (acc re-seeded by FIRST next tile)
            int lcv[16];
#pragma unroll
            for (int m = 0; m < 4; ++m) {
                const int4 v = *(const int4*)&Ls[t * 128 + wr * 64 + m * 16 + fq * 4];
                lcv[m * 4 + 0] = v.x; lcv[m * 4 + 1] = v.y;
                lcv[m * 4 + 2] = v.z; lcv[m * 4 + 3] = v.w;
            }
#pragma unroll
            for (int n = 0; n < 4; ++n) {
#pragma unroll
                for (int m = 0; m < 4; ++m)
#pragma unroll
                    for (int r = 0; r < 4; ++r) {
                        const float sv = acc[m][n][r];
                        const float sel = (lcv[m * 4 + r] != la[n]) ? sv : -INFINITY;
                        mN[n] = fmaxf(mN[n], sel);
                        m1[n] = fmaxf(m1[n], (sel < hiv[n]) ? sel : -INFINITY);
                    }
            }
        }
        __builtin_amdgcn_s_barrier();
    }
#undef STAGE
#undef COMPUTE

    // reduce the 4 candidate row-groups (lanes l, l^16, l^32, l^48 share anchor)
#pragma unroll
    for (int n = 0; n < 4; ++n) {
        mN[n] = fmaxf(mN[n], __shfl_xor(mN[n], 16));
        mN[n] = fmaxf(mN[n], __shfl_xor(mN[n], 32));
        m1[n] = fmaxf(m1[n], __shfl_xor(m1[n], 16));
        m1[n] = fmaxf(m1[n], __shfl_xor(m1[n], 32));
    }
    if (fq == 0) {
#pragma unroll
        for (int n = 0; n < 4; ++n) {
            RedN[wr][wc * 64 + n * 16 + frow] = mN[n];
            RedS[wr][wc * 64 + n * 16 + frow] = m1[n];
        }
    }
    __syncthreads();
    if (tid < 128) {   // combine the two candidate halves, write partials
        pMN[slice * NN + a0 + tid] = fmaxf(RedN[0][tid], RedN[1][tid]);
        pM1[slice * NN + a0 + tid] = fmaxf(RedS[0][tid], RedS[1][tid]);
    }
}

// ---------- kernel 5: combine slices -> per-block partial sums ----------
__global__ void kcombine(const int* __restrict__ posidx, const float* __restrict__ dap,
                         const float* __restrict__ pM1, const float* __restrict__ pMN,
                         float* __restrict__ partials)
{
    const int i = blockIdx.x * 256 + threadIdx.x;
    float loss = 0.0f, cnt = 0.0f;
    if (posidx[i] >= 0) {
        float s1 = -INFINITY, sN = -INFINITY;
#pragma unroll
        for (int s = 0; s < SL; ++s) {
            s1 = fmaxf(s1, pM1[s * NN + i]);
            sN = fmaxf(sN, pMN[s * NN + i]);
        }
        const float da = dap[i];
        const float lo = 1.0f - da - MARGIN;
        const float M = (s1 > lo) ? s1 : sN;   // has_semi ? best semi : hardest
        const float dan = fminf(fmaxf(1.0f - M, 0.0f), 2.0f);
        loss = fmaxf(da - dan + MARGIN, 0.0f);
        cnt = 1.0f;
    }
#pragma unroll
    for (int off = 1; off < 64; off <<= 1) {
        loss += __shfl_xor(loss, off);
        cnt  += __shfl_xor(cnt, off);
    }
    __shared__ float sl[4], sc[4];
    const int wave = threadIdx.x >> 6, lane = threadIdx.x & 63;
    if (lane == 0) { sl[wave] = loss; sc[wave] = cnt; }
    __syncthreads();
    if (threadIdx.x == 0) {
        partials[blockIdx.x]      = sl[0] + sl[1] + sl[2] + sl[3];
        partials[32 + blockIdx.x] = sc[0] + sc[1] + sc[2] + sc[3];
    }
}

// ---------- kernel 6: final scalar ----------
__global__ void kfinal(const float* __restrict__ partials, float* __restrict__ out) {
    const int t = threadIdx.x;  // 64
    float L = (t < 32) ? partials[t] : 0.0f;
    float C = (t < 32) ? partials[32 + t] : 0.0f;
#pragma unroll
    for (int off = 1; off < 64; off <<= 1) {
        L += __shfl_xor(L, off);
        C += __shfl_xor(C, off);
    }
    if (t == 0) out[0] = (C > 0.0f) ? (L / C) : 0.0f;
}

extern "C" void kernel_launch(void* const* d_in, const int* in_sizes, int n_in,
                              void* d_out, int out_size, void* d_ws, size_t ws_size,
                              hipStream_t stream) {
    const float* emb  = (const float*)d_in[0];
    const int* labels = (const int*)d_in[1];
    float* out = (float*)d_out;

    char* w = (char*)d_ws;
    u8*    E8   = (u8*)w;                        w += (size_t)NN * DD;       // 2 MB
    float* invn = (float*)w;                     w += NN * 4;
    float* dapv = (float*)w;                     w += NN * 4;
    int*   posi = (int*)w;                       w += NN * 4;
    float* pM1  = (float*)w;                     w += (size_t)SL * NN * 4;   // 512 KB
    float* pMN  = (float*)w;                     w += (size_t)SL * NN * 4;   // 512 KB
    float* parts = (float*)w;

    kprepclass<<<2048 + 128, 256, 0, stream>>>(emb, labels, E8, invn, posi);
    kdap<<<NN / 4, 256, 0, stream>>>(emb, invn, posi, dapv);
    kmine<<<dim3(SL, NN / 128), 256, 0, stream>>>(E8, labels, dapv, pM1, pMN);
    kcombine<<<NN / 256, 256, 0, stream>>>(posi, dapv, pM1, pMN, parts);
    kfinal<<<1, 64, 0, stream>>>(parts, out);
}